// Round 7
// baseline (457.643 us; speedup 1.0000x reference)
//
#include <hip/hip_runtime.h>
#include <hip/hip_bf16.h>

// Problem constants (B, H, N, D, W) = (2, 12, 2048, 128, 64)
constexpr int Bc = 2;
constexpr int Hc = 12;
constexpr int Nc = 2048;   // power of two
constexpr int Dc = 128;
constexpr int Wc = 64;
constexpr float SCALE = 0.08838834764831845f;  // 1/sqrt(128)
constexpr int ELEMS = Bc * Hc * Nc * Dc;       // 6,291,456 per tensor

__device__ __forceinline__ float bf_lo(unsigned u) {
    u <<= 16;
    return __builtin_bit_cast(float, u);
}
__device__ __forceinline__ float bf_hi(unsigned u) {
    u &= 0xffff0000u;
    return __builtin_bit_cast(float, u);
}
__device__ __forceinline__ unsigned short f2bf(float f) {
    __hip_bfloat16 h = __float2bfloat16(f);   // RNE
    return __builtin_bit_cast(unsigned short, h);
}

// ---------- fp32 -> bf16 staging for k and v ----------
__global__ __launch_bounds__(256) void cvt_kernel(
    const float* __restrict__ k,
    const float* __restrict__ v,
    unsigned short* __restrict__ kb,
    unsigned short* __restrict__ vb)
{
    const int i = blockIdx.x * 256 + threadIdx.x;   // float4 index
    const float4 kk = ((const float4*)k)[i];
    const float4 vv = ((const float4*)v)[i];
    ushort4 ko, vo;
    ko.x = f2bf(kk.x); ko.y = f2bf(kk.y); ko.z = f2bf(kk.z); ko.w = f2bf(kk.w);
    vo.x = f2bf(vv.x); vo.y = f2bf(vv.y); vo.z = f2bf(vv.z); vo.w = f2bf(vv.w);
    ((ushort4*)kb)[i] = ko;
    ((ushort4*)vb)[i] = vo;
}

// ---------- wave-per-row gather attention: zero LDS, 128B-granular loads ----
// Wave (64 lanes) owns one query row.
//  XCD-aware swizzle: 24 heads = 8 XCDs x 3 heads. Assuming round-robin
//  blockIdx%8 -> XCD dispatch, bh = (i&7) + 8*((i>>3)%3) pins each head's
//  1 MB k+v gather set to one XCD's 4 MB L2 (3.1 MB/XCD working set).
//  QK:  8 passes of 8 columns; 8 lanes (octet) per column, each lane 16B ->
//       every k-row request is 128B-contiguous (2 per 256B row).
//  Softmax: octet-redundant butterfly over xor 8,16,32.
//  PV:  4 groups x 16 lanes; full 256B v-row per group-iter (16B/lane);
//       cross-group shfl_xor(16,32); lanes 0..15 store 32B each.
__global__ __launch_bounds__(256, 8) void sca_wave_kernel(
    const float* __restrict__ q,
    const unsigned short* __restrict__ kb,
    const unsigned short* __restrict__ vb,
    const int*   __restrict__ col_ids,
    float*       __restrict__ out)
{
    const int t    = threadIdx.x;
    const int wv   = t >> 6;                 // wave 0..3 (independent)
    const int lane = t & 63;

    // ---- XCD-aware row mapping ----
    const int i    = blockIdx.x;             // 0..12287
    const int xcd  = i & 7;
    const int slot = i >> 3;                 // 0..1535
    const int hg   = slot % 3;               // head group 0..2
    const int nb   = slot / 3;               // 0..511
    const int bh   = xcd + 8 * hg;           // 0..23  (3 heads per XCD)
    const int n    = nb * 4 + wv;            // 0..2047
    const int row  = bh * Nc + n;

    const int c_own = col_ids[n * Wc + lane];   // lane owns column `lane`

    const float*          qrow  = q  + (size_t)row * Dc;
    const unsigned short* kbase = kb + (size_t)bh * Nc * Dc;
    const unsigned short* vbase = vb + (size_t)bh * Nc * Dc;

    const int p8 = lane & 7;                 // position within octet
    const int o8 = lane >> 3;                // octet 0..7
    const int g  = lane >> 4;                // PV group 0..3
    const int j  = lane & 15;                // 16B chunk within 256B v-row

    // q cache: dims 8*p8..8*p8+7 (first row half) and 64+8*p8.. (second half)
    const float4* q4 = (const float4*)qrow;
    const float4 qa0 = q4[2 * p8];
    const float4 qa1 = q4[2 * p8 + 1];
    const float4 qb0 = q4[16 + 2 * p8];
    const float4 qb1 = q4[16 + 2 * p8 + 1];

    // ---------- QK: 8 passes of 8 columns, 128B-granular ----------
    float sc[8];
#pragma unroll
    for (int P = 0; P < 8; ++P) {
        const int cc = __shfl(c_own, 8 * P + o8);
        const uint4* krow = (const uint4*)(kbase + (size_t)cc * Dc);
        const uint4 k0 = krow[p8];           // octet covers bytes 0..127
        const uint4 k1 = krow[8 + p8];       // octet covers bytes 128..255
        float acc =
              bf_lo(k0.x) * qa0.x + bf_hi(k0.x) * qa0.y
            + bf_lo(k0.y) * qa0.z + bf_hi(k0.y) * qa0.w
            + bf_lo(k0.z) * qa1.x + bf_hi(k0.z) * qa1.y
            + bf_lo(k0.w) * qa1.z + bf_hi(k0.w) * qa1.w
            + bf_lo(k1.x) * qb0.x + bf_hi(k1.x) * qb0.y
            + bf_lo(k1.y) * qb0.z + bf_hi(k1.y) * qb0.w
            + bf_lo(k1.z) * qb1.x + bf_hi(k1.z) * qb1.y
            + bf_lo(k1.w) * qb1.z + bf_hi(k1.w) * qb1.w;
        acc += __shfl_xor(acc, 1);
        acc += __shfl_xor(acc, 2);
        acc += __shfl_xor(acc, 4);
        sc[P] = acc * SCALE;                 // col 8P + o8, octet-redundant
    }

    // ---------- softmax (octet-redundant butterfly) ----------
    float m = sc[0];
#pragma unroll
    for (int P = 1; P < 8; ++P) m = fmaxf(m, sc[P]);
#pragma unroll
    for (int off = 8; off < 64; off <<= 1) m = fmaxf(m, __shfl_xor(m, off));
    float e[8];
    float s = 0.0f;
#pragma unroll
    for (int P = 0; P < 8; ++P) { e[P] = __expf(sc[P] - m); s += e[P]; }
#pragma unroll
    for (int off = 8; off < 64; off <<= 1) s += __shfl_xor(s, off);
    const float inv = 1.0f / s;
    float pn[8];
#pragma unroll
    for (int P = 0; P < 8; ++P) pn[P] = e[P] * inv;

    // ---------- PV: 4 groups x 16 lanes, full 256B v-row per group-iter ----
    float4 accA = make_float4(0.f, 0.f, 0.f, 0.f);   // dims 8j .. 8j+3
    float4 accB = make_float4(0.f, 0.f, 0.f, 0.f);   // dims 8j+4 .. 8j+7
#pragma unroll
    for (int ii = 0; ii < 16; ++ii) {
        const int cc = __shfl(c_own, 4 * ii + g);    // col w = 4*ii+g
        // owner octet of col w is w&7 = 4*(ii&1)+g; element index = w>>3 = ii>>1
        const float pr = __shfl(pn[ii >> 1], 32 * (ii & 1) + 8 * g);
        const uint4 vv = ((const uint4*)(vbase + (size_t)cc * Dc))[j];
        accA.x += pr * bf_lo(vv.x);
        accA.y += pr * bf_hi(vv.x);
        accA.z += pr * bf_lo(vv.y);
        accA.w += pr * bf_hi(vv.y);
        accB.x += pr * bf_lo(vv.z);
        accB.y += pr * bf_hi(vv.z);
        accB.z += pr * bf_lo(vv.w);
        accB.w += pr * bf_hi(vv.w);
    }
    // combine the four groups (same j on lanes j, 16+j, 32+j, 48+j)
#pragma unroll
    for (int off = 16; off <= 32; off <<= 1) {
        accA.x += __shfl_xor(accA.x, off);
        accA.y += __shfl_xor(accA.y, off);
        accA.z += __shfl_xor(accA.z, off);
        accA.w += __shfl_xor(accA.w, off);
        accB.x += __shfl_xor(accB.x, off);
        accB.y += __shfl_xor(accB.y, off);
        accB.z += __shfl_xor(accB.z, off);
        accB.w += __shfl_xor(accB.w, off);
    }

    if (lane < 16) {
        float4* orow = (float4*)(out + (size_t)row * Dc);
        orow[2 * j]     = accA;
        orow[2 * j + 1] = accB;
    }
}

// ---------- fallback: fp32 kernel (used only if ws too small) ----------
__global__ __launch_bounds__(256) void sca_kernel(
    const float* __restrict__ q,
    const float* __restrict__ k,
    const float* __restrict__ v,
    const int*   __restrict__ col_ids,
    float*       __restrict__ out)
{
    const int bid = blockIdx.x;
    const int n   = bid & (Nc - 1);
    const int bh  = bid >> 11;
    const int t   = threadIdx.x;

    __shared__ int   s_cols[Wc];
    __shared__ float s_scores[Wc];
    __shared__ float s_probs[Wc];
    __shared__ float s_red[8 * Dc];

    if (t < Wc) s_cols[t] = col_ids[n * Wc + t];

    const float* qrow  = q + ((size_t)bh * Nc + n) * Dc;
    const float* kbase = k + (size_t)bh * Nc * Dc;
    const float* vbase = v + (size_t)bh * Nc * Dc;

    __syncthreads();
    {
        const int w = t >> 2;
        const int p = t & 3;
        const int c = s_cols[w];
        const float4* krow = (const float4*)(kbase + (size_t)c * Dc);
        const float4* q4   = (const float4*)qrow;
        float acc = 0.0f;
#pragma unroll
        for (int i = 0; i < 8; ++i) {
            const float4 kk = krow[p + 4 * i];
            const float4 qq = q4[p + 4 * i];
            acc += kk.x * qq.x + kk.y * qq.y + kk.z * qq.z + kk.w * qq.w;
        }
        acc += __shfl_xor(acc, 1);
        acc += __shfl_xor(acc, 2);
        if (p == 0) s_scores[w] = acc * SCALE;
    }
    __syncthreads();
    if (t < 64) {
        const float sv = s_scores[t];
        float m = sv;
#pragma unroll
        for (int off = 32; off > 0; off >>= 1) m = fmaxf(m, __shfl_xor(m, off));
        const float e = __expf(sv - m);
        float l = e;
#pragma unroll
        for (int off = 32; off > 0; off >>= 1) l += __shfl_xor(l, off);
        s_probs[t] = e / l;
    }
    __syncthreads();
    {
        const int j = t & 31;
        const int g = t >> 5;
        float4 acc = make_float4(0.f, 0.f, 0.f, 0.f);
#pragma unroll
        for (int i = 0; i < 8; ++i) {
            const int w  = g * 8 + i;
            const float pr = s_probs[w];
            const int   c  = s_cols[w];
            const float4 vv = ((const float4*)(vbase + (size_t)c * Dc))[j];
            acc.x += pr * vv.x;
            acc.y += pr * vv.y;
            acc.z += pr * vv.z;
            acc.w += pr * vv.w;
        }
        ((float4*)s_red)[g * 32 + j] = acc;
    }
    __syncthreads();
    if (t < Dc) {
        float sv = 0.0f;
#pragma unroll
        for (int g = 0; g < 8; ++g) sv += s_red[g * Dc + t];
        out[((size_t)bh * Nc + n) * Dc + t] = sv;
    }
}

extern "C" void kernel_launch(void* const* d_in, const int* in_sizes, int n_in,
                              void* d_out, int out_size, void* d_ws, size_t ws_size,
                              hipStream_t stream) {
    const float* q       = (const float*)d_in[0];
    const float* k       = (const float*)d_in[1];
    const float* v       = (const float*)d_in[2];
    const int*   col_ids = (const int*)  d_in[3];
    float*       out     = (float*)d_out;

    const int n_rows = Bc * Hc * Nc;                 // 49152 rows
    const size_t need = (size_t)2 * ELEMS * sizeof(unsigned short);  // 25.2 MB

    if (ws_size >= need) {
        unsigned short* kbp = (unsigned short*)d_ws;
        unsigned short* vbp = kbp + ELEMS;
        cvt_kernel<<<dim3(ELEMS / 4 / 256), dim3(256), 0, stream>>>(k, v, kbp, vbp);
        sca_wave_kernel<<<dim3(n_rows / 4), dim3(256), 0, stream>>>(q, kbp, vbp, col_ids, out);
    } else {
        sca_kernel<<<dim3(n_rows), dim3(256), 0, stream>>>(q, k, v, col_ids, out);
    }
}

// Round 8
// 184.079 us; speedup vs baseline: 2.4861x; 2.4861x over previous
//
#include <hip/hip_runtime.h>
#include <hip/hip_bf16.h>

// Problem constants (B, H, N, D, W) = (2, 12, 2048, 128, 64)
constexpr int Bc = 2;
constexpr int Hc = 12;
constexpr int Nc = 2048;   // power of two
constexpr int Dc = 128;
constexpr int Wc = 64;
constexpr float SCALE = 0.08838834764831845f;  // 1/sqrt(128)
constexpr int ELEMS = Bc * Hc * Nc * Dc;       // 6,291,456 per tensor

__device__ __forceinline__ float bf_lo(unsigned u) {
    u <<= 16;
    return __builtin_bit_cast(float, u);
}
__device__ __forceinline__ float bf_hi(unsigned u) {
    u &= 0xffff0000u;
    return __builtin_bit_cast(float, u);
}
__device__ __forceinline__ unsigned short f2bf(float f) {
    __hip_bfloat16 h = __float2bfloat16(f);   // RNE
    return __builtin_bit_cast(unsigned short, h);
}

// ---------- fp32 -> bf16 staging for k and v ----------
__global__ __launch_bounds__(256) void cvt_kernel(
    const float* __restrict__ k,
    const float* __restrict__ v,
    unsigned short* __restrict__ kb,
    unsigned short* __restrict__ vb)
{
    const int i = blockIdx.x * 256 + threadIdx.x;   // float4 index
    const float4 kk = ((const float4*)k)[i];
    const float4 vv = ((const float4*)v)[i];
    ushort4 ko, vo;
    ko.x = f2bf(kk.x); ko.y = f2bf(kk.y); ko.z = f2bf(kk.z); ko.w = f2bf(kk.w);
    vo.x = f2bf(vv.x); vo.y = f2bf(vv.y); vo.z = f2bf(vv.z); vo.w = f2bf(vv.w);
    ((ushort4*)kb)[i] = ko;
    ((ushort4*)vb)[i] = vo;
}

// ---------- wave-per-row gather attention: zero LDS, 128B-granular loads ----
// Wave (64 lanes) owns one query row.
//  XCD-aware swizzle: 24 heads = 8 XCDs x 3 heads. Assuming round-robin
//  blockIdx%8 -> XCD dispatch, bh = (i&7) + 8*((i>>3)%3) pins each head's
//  k+v gather set to one XCD's 4 MB L2 (3.1 MB/XCD working set).
//  NOTE: plain __launch_bounds__(256). R7's (256,8) forced 32 VGPRs and
//  spilled sc[]/e[]/pn[] to scratch: 872 MB WRITE_SIZE, 4x slower. VGPR=52
//  needs no cap.
//  QK:  8 passes of 8 columns; 8 lanes (octet) per column, each lane 16B ->
//       every k-row request is 128B-contiguous (2 per 256B row).
//  Softmax: octet-redundant butterfly over xor 8,16,32.
//  PV:  4 groups x 16 lanes; full 256B v-row per group-iter (16B/lane);
//       cross-group shfl_xor(16,32); lanes 0..15 store 32B each.
__global__ __launch_bounds__(256) void sca_wave_kernel(
    const float* __restrict__ q,
    const unsigned short* __restrict__ kb,
    const unsigned short* __restrict__ vb,
    const int*   __restrict__ col_ids,
    float*       __restrict__ out)
{
    const int t    = threadIdx.x;
    const int wv   = t >> 6;                 // wave 0..3 (independent)
    const int lane = t & 63;

    // ---- XCD-aware row mapping ----
    const int i    = blockIdx.x;             // 0..12287
    const int xcd  = i & 7;
    const int slot = i >> 3;                 // 0..1535
    const int hg   = slot % 3;               // head group 0..2
    const int nb   = slot / 3;               // 0..511
    const int bh   = xcd + 8 * hg;           // 0..23  (3 heads per XCD)
    const int n    = nb * 4 + wv;            // 0..2047
    const int row  = bh * Nc + n;

    const int c_own = col_ids[n * Wc + lane];   // lane owns column `lane`

    const float*          qrow  = q  + (size_t)row * Dc;
    const unsigned short* kbase = kb + (size_t)bh * Nc * Dc;
    const unsigned short* vbase = vb + (size_t)bh * Nc * Dc;

    const int p8 = lane & 7;                 // position within octet
    const int o8 = lane >> 3;                // octet 0..7
    const int g  = lane >> 4;                // PV group 0..3
    const int j  = lane & 15;                // 16B chunk within 256B v-row

    // q cache: dims 8*p8..8*p8+7 (first row half) and 64+8*p8.. (second half)
    const float4* q4 = (const float4*)qrow;
    const float4 qa0 = q4[2 * p8];
    const float4 qa1 = q4[2 * p8 + 1];
    const float4 qb0 = q4[16 + 2 * p8];
    const float4 qb1 = q4[16 + 2 * p8 + 1];

    // ---------- QK: 8 passes of 8 columns, 128B-granular ----------
    float sc[8];
#pragma unroll
    for (int P = 0; P < 8; ++P) {
        const int cc = __shfl(c_own, 8 * P + o8);
        const uint4* krow = (const uint4*)(kbase + (size_t)cc * Dc);
        const uint4 k0 = krow[p8];           // octet covers bytes 0..127
        const uint4 k1 = krow[8 + p8];       // octet covers bytes 128..255
        float acc =
              bf_lo(k0.x) * qa0.x + bf_hi(k0.x) * qa0.y
            + bf_lo(k0.y) * qa0.z + bf_hi(k0.y) * qa0.w
            + bf_lo(k0.z) * qa1.x + bf_hi(k0.z) * qa1.y
            + bf_lo(k0.w) * qa1.z + bf_hi(k0.w) * qa1.w
            + bf_lo(k1.x) * qb0.x + bf_hi(k1.x) * qb0.y
            + bf_lo(k1.y) * qb0.z + bf_hi(k1.y) * qb0.w
            + bf_lo(k1.z) * qb1.x + bf_hi(k1.z) * qb1.y
            + bf_lo(k1.w) * qb1.z + bf_hi(k1.w) * qb1.w;
        acc += __shfl_xor(acc, 1);
        acc += __shfl_xor(acc, 2);
        acc += __shfl_xor(acc, 4);
        sc[P] = acc * SCALE;                 // col 8P + o8, octet-redundant
    }

    // ---------- softmax (octet-redundant butterfly) ----------
    float m = sc[0];
#pragma unroll
    for (int P = 1; P < 8; ++P) m = fmaxf(m, sc[P]);
#pragma unroll
    for (int off = 8; off < 64; off <<= 1) m = fmaxf(m, __shfl_xor(m, off));
    float e[8];
    float s = 0.0f;
#pragma unroll
    for (int P = 0; P < 8; ++P) { e[P] = __expf(sc[P] - m); s += e[P]; }
#pragma unroll
    for (int off = 8; off < 64; off <<= 1) s += __shfl_xor(s, off);
    const float inv = 1.0f / s;
    float pn[8];
#pragma unroll
    for (int P = 0; P < 8; ++P) pn[P] = e[P] * inv;

    // ---------- PV: 4 groups x 16 lanes, full 256B v-row per group-iter ----
    float4 accA = make_float4(0.f, 0.f, 0.f, 0.f);   // dims 8j .. 8j+3
    float4 accB = make_float4(0.f, 0.f, 0.f, 0.f);   // dims 8j+4 .. 8j+7
#pragma unroll
    for (int ii = 0; ii < 16; ++ii) {
        const int cc = __shfl(c_own, 4 * ii + g);    // col w = 4*ii+g
        // owner octet of col w is w&7 = 4*(ii&1)+g; element index = w>>3 = ii>>1
        const float pr = __shfl(pn[ii >> 1], 32 * (ii & 1) + 8 * g);
        const uint4 vv = ((const uint4*)(vbase + (size_t)cc * Dc))[j];
        accA.x += pr * bf_lo(vv.x);
        accA.y += pr * bf_hi(vv.x);
        accA.z += pr * bf_lo(vv.y);
        accA.w += pr * bf_hi(vv.y);
        accB.x += pr * bf_lo(vv.z);
        accB.y += pr * bf_hi(vv.z);
        accB.z += pr * bf_lo(vv.w);
        accB.w += pr * bf_hi(vv.w);
    }
    // combine the four groups (same j on lanes j, 16+j, 32+j, 48+j)
#pragma unroll
    for (int off = 16; off <= 32; off <<= 1) {
        accA.x += __shfl_xor(accA.x, off);
        accA.y += __shfl_xor(accA.y, off);
        accA.z += __shfl_xor(accA.z, off);
        accA.w += __shfl_xor(accA.w, off);
        accB.x += __shfl_xor(accB.x, off);
        accB.y += __shfl_xor(accB.y, off);
        accB.z += __shfl_xor(accB.z, off);
        accB.w += __shfl_xor(accB.w, off);
    }

    if (lane < 16) {
        float4* orow = (float4*)(out + (size_t)row * Dc);
        orow[2 * j]     = accA;
        orow[2 * j + 1] = accB;
    }
}

// ---------- fallback: fp32 kernel (used only if ws too small) ----------
__global__ __launch_bounds__(256) void sca_kernel(
    const float* __restrict__ q,
    const float* __restrict__ k,
    const float* __restrict__ v,
    const int*   __restrict__ col_ids,
    float*       __restrict__ out)
{
    const int bid = blockIdx.x;
    const int n   = bid & (Nc - 1);
    const int bh  = bid >> 11;
    const int t   = threadIdx.x;

    __shared__ int   s_cols[Wc];
    __shared__ float s_scores[Wc];
    __shared__ float s_probs[Wc];
    __shared__ float s_red[8 * Dc];

    if (t < Wc) s_cols[t] = col_ids[n * Wc + t];

    const float* qrow  = q + ((size_t)bh * Nc + n) * Dc;
    const float* kbase = k + (size_t)bh * Nc * Dc;
    const float* vbase = v + (size_t)bh * Nc * Dc;

    __syncthreads();
    {
        const int w = t >> 2;
        const int p = t & 3;
        const int c = s_cols[w];
        const float4* krow = (const float4*)(kbase + (size_t)c * Dc);
        const float4* q4   = (const float4*)qrow;
        float acc = 0.0f;
#pragma unroll
        for (int i = 0; i < 8; ++i) {
            const float4 kk = krow[p + 4 * i];
            const float4 qq = q4[p + 4 * i];
            acc += kk.x * qq.x + kk.y * qq.y + kk.z * qq.z + kk.w * qq.w;
        }
        acc += __shfl_xor(acc, 1);
        acc += __shfl_xor(acc, 2);
        if (p == 0) s_scores[w] = acc * SCALE;
    }
    __syncthreads();
    if (t < 64) {
        const float sv = s_scores[t];
        float m = sv;
#pragma unroll
        for (int off = 32; off > 0; off >>= 1) m = fmaxf(m, __shfl_xor(m, off));
        const float e = __expf(sv - m);
        float l = e;
#pragma unroll
        for (int off = 32; off > 0; off >>= 1) l += __shfl_xor(l, off);
        s_probs[t] = e / l;
    }
    __syncthreads();
    {
        const int j = t & 31;
        const int g = t >> 5;
        float4 acc = make_float4(0.f, 0.f, 0.f, 0.f);
#pragma unroll
        for (int i = 0; i < 8; ++i) {
            const int w  = g * 8 + i;
            const float pr = s_probs[w];
            const int   c  = s_cols[w];
            const float4 vv = ((const float4*)(vbase + (size_t)c * Dc))[j];
            acc.x += pr * vv.x;
            acc.y += pr * vv.y;
            acc.z += pr * vv.z;
            acc.w += pr * vv.w;
        }
        ((float4*)s_red)[g * 32 + j] = acc;
    }
    __syncthreads();
    if (t < Dc) {
        float sv = 0.0f;
#pragma unroll
        for (int g = 0; g < 8; ++g) sv += s_red[g * Dc + t];
        out[((size_t)bh * Nc + n) * Dc + t] = sv;
    }
}

extern "C" void kernel_launch(void* const* d_in, const int* in_sizes, int n_in,
                              void* d_out, int out_size, void* d_ws, size_t ws_size,
                              hipStream_t stream) {
    const float* q       = (const float*)d_in[0];
    const float* k       = (const float*)d_in[1];
    const float* v       = (const float*)d_in[2];
    const int*   col_ids = (const int*)  d_in[3];
    float*       out     = (float*)d_out;

    const int n_rows = Bc * Hc * Nc;                 // 49152 rows
    const size_t need = (size_t)2 * ELEMS * sizeof(unsigned short);  // 25.2 MB

    if (ws_size >= need) {
        unsigned short* kbp = (unsigned short*)d_ws;
        unsigned short* vbp = kbp + ELEMS;
        cvt_kernel<<<dim3(ELEMS / 4 / 256), dim3(256), 0, stream>>>(k, v, kbp, vbp);
        sca_wave_kernel<<<dim3(n_rows / 4), dim3(256), 0, stream>>>(q, kbp, vbp, col_ids, out);
    } else {
        sca_kernel<<<dim3(n_rows), dim3(256), 0, stream>>>(q, k, v, col_ids, out);
    }
}